// Round 15
// baseline (682.773 us; speedup 1.0000x reference)
//
#include <hip/hip_runtime.h>
#include <hip/hip_bf16.h>

#define NNODES 8192
#define NEDGES 262144
#define HDIM 128
#define NLAYERS 6
#define NMASK (NNODES - 1)

typedef __attribute__((ext_vector_type(8))) short bf16x8;   // 8 bf16 = 4 VGPR
typedef __attribute__((ext_vector_type(4))) float f32x4;    // MFMA acc
typedef const __attribute__((address_space(1))) void gvoid;
typedef __attribute__((address_space(3))) void svoid;

// fast silu: v_rcp instead of precise-div sequence (~1 ulp rcp, fine at bf16 out)
__device__ __forceinline__ float silu_f(float x) {
    return x * __builtin_amdgcn_rcpf(1.0f + __expf(-x));
}
// fast fp32->bf16: round-half-away via +0x8000 (2 VALU ops; inputs finite)
__device__ __forceinline__ unsigned short f2bu(float x) {
    unsigned int u; __builtin_memcpy(&u, &x, 4);
    return (unsigned short)((u + 0x8000u) >> 16);
}
__device__ __forceinline__ float bu2f(unsigned short u) {
    unsigned int v = ((unsigned int)u) << 16;
    float f; __builtin_memcpy(&f, &v, 4);
    return f;
}

// cooperative stage of one 16KB slice-PAIR (8192 shorts) into LDS:
// each wave moves 4KB via 4 x 1KB global_load_lds.
__device__ __forceinline__ void stage_pair(const unsigned short* src,
                                           unsigned short* dst, int w) {
    const unsigned short* s = src + w * 2048;
    unsigned short* d = dst + w * 2048;
    __builtin_amdgcn_global_load_lds((gvoid*)s, (svoid*)d, 16, 0, 0);
    __builtin_amdgcn_global_load_lds((gvoid*)(s + 512), (svoid*)(d + 512), 16, 0, 0);
    __builtin_amdgcn_global_load_lds((gvoid*)(s + 1024), (svoid*)(d + 1024), 16, 0, 0);
    __builtin_amdgcn_global_load_lds((gvoid*)(s + 1536), (svoid*)(d + 1536), 16, 0, 0);
}

// Cb XOR swizzle (T2-style): byte ^= (row&7)<<4. Keeps 16B chunks intact
// (bits 4-6 only), stride-256B row accesses 2-way-or-free (R13/R14 verified;
// conflicts 803k -> 524k).
__device__ __forceinline__ int cb_byte(int row, int colshort) {
    return ((row << 8) + (colshort << 1)) ^ ((row & 7) << 4);
}

// is64 probe, inlined: int64 edge_index has zero high words at ei32[1,3,5,7].
__device__ __forceinline__ int probe_is64(const int* ei32) {
    return (ei32[1] == 0 && ei32[3] == 0 && ei32[5] == 0 && ei32[7] == 0) ? 1 : 0;
}
__device__ __forceinline__ int load_idx(const void* ei, int is64, int i) {
    int v = is64 ? (int)(((const long long*)ei)[i]) : ((const int*)ei)[i];
    return v & NMASK;
}

// ---------------------------------------------------------------- edge sort (counting sort by row)
// cnt pass also performs pos_init (independent work, merged to save a launch)
__global__ void cnt_kernel(const void* __restrict__ ei,
                           int* __restrict__ cnt,
                           const float* __restrict__ pin, float* __restrict__ pos) {
    int i = blockIdx.x * blockDim.x + threadIdx.x;
    if (i < NNODES * 3) pos[i] = pin[i];
    if (i < NEDGES) {
        const int is64 = probe_is64((const int*)ei);
        atomicAdd(&cnt[load_idx(ei, is64, i)], 1);
    }
}
__global__ void scan_kernel(const int* __restrict__ cnt, int* __restrict__ woff,
                            float* __restrict__ deg) {
    __shared__ int sums[256];
    const int t = threadIdx.x;
    const int base = t * 32;
    int s = 0;
#pragma unroll
    for (int i = 0; i < 32; ++i) s += cnt[base + i];
    sums[t] = s;
    __syncthreads();
    if (t == 0) {
        int run = 0;
        for (int k = 0; k < 256; ++k) { int v = sums[k]; sums[k] = run; run += v; }
    }
    __syncthreads();
    int run = sums[t];
#pragma unroll
    for (int i = 0; i < 32; ++i) {
        int c = cnt[base + i];
        woff[base + i] = run;
        deg[base + i] = (float)c;
        run += c;
    }
}
__global__ void scatter_kernel(const void* __restrict__ ei,
                               int* __restrict__ woff,
                               int* __restrict__ rowS, int* __restrict__ colS) {
    int i = blockIdx.x * blockDim.x + threadIdx.x;
    if (i < NEDGES) {
        const int is64 = probe_is64((const int*)ei);
        int r = load_idx(ei, is64, i);
        int c = load_idx(ei, is64, NEDGES + i);
        int p = atomicAdd(&woff[r], 1);
        rowS[p] = r;
        colS[p] = c;
    }
}

// ---------------------------------------------------------------- weight prep
// Unified edge-weight table: per layer 16 slices of [4 chunk][128 n][8 k]
// (slices 0-7 = eW1, 8-11 = eW2, 12-15 = cW1). k = sl*32 + ch*8 + j.
__global__ void prep_weights_kernel(const float* __restrict__ eW1,
                                    const float* __restrict__ eW2,
                                    const float* __restrict__ cW1,
                                    const float* __restrict__ nW1,
                                    const float* __restrict__ nW2,
                                    unsigned short* __restrict__ ewt,
                                    unsigned short* __restrict__ n1tb,
                                    unsigned short* __restrict__ n2tb,
                                    float* __restrict__ w1d) {
    const int TB = NLAYERS * 8 * 4 * 128 * 8;   // 196608
    const int TS = NLAYERS * 4 * 4 * 128 * 8;   // 98304
    const int TD = NLAYERS * 128;
    const int TOT = 2 * TB + 3 * TS + TD;
    for (int i = blockIdx.x * blockDim.x + threadIdx.x; i < TOT;
         i += gridDim.x * blockDim.x) {
        if (i < TB) {
            int j = i & 7, r = i >> 3;
            int n = r & 127; r >>= 7;
            int ch = r & 3; r >>= 2;
            int sl = r & 7; int l = r >> 3;
            int k = sl * 32 + ch * 8 + j;
            ewt[(size_t)(l * 16 + sl) * 4096 + ch * 1024 + n * 8 + j] =
                f2bu(eW1[((size_t)l * 257 + k) * 128 + n]);
        } else if (i < TB + TS) {
            int q = i - TB;
            int j = q & 7, r = q >> 3;
            int n = r & 127; r >>= 7;
            int ch = r & 3; r >>= 2;
            int sl = r & 3; int l = r >> 2;
            int k = sl * 32 + ch * 8 + j;
            ewt[(size_t)(l * 16 + 8 + sl) * 4096 + ch * 1024 + n * 8 + j] =
                f2bu(eW2[((size_t)l * 128 + k) * 128 + n]);
        } else if (i < TB + 2 * TS) {
            int q = i - TB - TS;
            int j = q & 7, r = q >> 3;
            int n = r & 127; r >>= 7;
            int ch = r & 3; r >>= 2;
            int sl = r & 3; int l = r >> 2;
            int k = sl * 32 + ch * 8 + j;
            ewt[(size_t)(l * 16 + 12 + sl) * 4096 + ch * 1024 + n * 8 + j] =
                f2bu(cW1[((size_t)l * 128 + k) * 128 + n]);
        } else if (i < 2 * TB + 2 * TS) {
            int q = i - TB - 2 * TS;
            int j = q & 7, r = q >> 3;
            int n = r & 127; r >>= 7;
            int ch = r & 3; r >>= 2;
            int sl = r & 7; int l = r >> 3;
            int k = sl * 32 + ch * 8 + j;
            n1tb[q] = f2bu(nW1[((size_t)l * 256 + k) * 128 + n]);
        } else if (i < 2 * TB + 3 * TS) {
            int q = i - 2 * TB - 2 * TS;
            int j = q & 7, r = q >> 3;
            int n = r & 127; r >>= 7;
            int ch = r & 3; r >>= 2;
            int sl = r & 3; int l = r >> 2;
            int k = sl * 32 + ch * 8 + j;
            n2tb[q] = f2bu(nW2[((size_t)l * 128 + k) * 128 + n]);
        } else {
            int r = i - 2 * TB - 3 * TS, l = r / 128, n = r % 128;
            w1d[r] = eW1[((size_t)l * 257 + 256) * 128 + n];
        }
    }
}

// ---------------------------------------------------------------- injection MLP (bf16 h out)
__global__ __launch_bounds__(256) void inj_kernel(
    const float* __restrict__ atom, const float* __restrict__ z,
    const float* __restrict__ W1, const float* __restrict__ b1,
    const float* __restrict__ W2, const float* __restrict__ b2,
    const float* __restrict__ W3, const float* __restrict__ b3,
    unsigned short* __restrict__ hb)
{
    __shared__ __align__(16) float in_s[16][84];
    __shared__ __align__(16) float s1[16][260];
    __shared__ __align__(16) float s2[16][132];
    const int tid = threadIdx.x;
    const int n0 = blockIdx.x * 16;

    if (tid < 80) {
        for (int e = 0; e < 16; ++e) {
            int n = n0 + e;
            in_s[e][tid] = (tid < 16) ? atom[n * 16 + tid] : z[(n >> 5) * 64 + (tid - 16)];
        }
    }
    __syncthreads();
    {
        float acc[16];
        float bias = b1[tid];
#pragma unroll
        for (int e = 0; e < 16; ++e) acc[e] = bias;
        for (int k4 = 0; k4 < 20; ++k4) {
            float w0 = W1[(k4 * 4 + 0) * 256 + tid];
            float w1 = W1[(k4 * 4 + 1) * 256 + tid];
            float w2 = W1[(k4 * 4 + 2) * 256 + tid];
            float w3 = W1[(k4 * 4 + 3) * 256 + tid];
#pragma unroll
            for (int e = 0; e < 16; ++e) {
                const float4 v = *(const float4*)&in_s[e][k4 * 4];
                acc[e] += v.x * w0 + v.y * w1 + v.z * w2 + v.w * w3;
            }
        }
#pragma unroll
        for (int e = 0; e < 16; ++e) s1[e][tid] = silu_f(acc[e]);
    }
    __syncthreads();
    const int j = tid & 127, hv = tid >> 7;
    {
        float acc[8];
        float bias = b2[j];
#pragma unroll
        for (int e = 0; e < 8; ++e) acc[e] = bias;
        for (int k4 = 0; k4 < 64; ++k4) {
            float w0 = W2[(k4 * 4 + 0) * 128 + j];
            float w1 = W2[(k4 * 4 + 1) * 128 + j];
            float w2 = W2[(k4 * 4 + 2) * 128 + j];
            float w3 = W2[(k4 * 4 + 3) * 128 + j];
#pragma unroll
            for (int e = 0; e < 8; ++e) {
                const float4 v = *(const float4*)&s1[hv * 8 + e][k4 * 4];
                acc[e] += v.x * w0 + v.y * w1 + v.z * w2 + v.w * w3;
            }
        }
#pragma unroll
        for (int e = 0; e < 8; ++e) s2[hv * 8 + e][j] = silu_f(acc[e]);
    }
    __syncthreads();
    {
        float acc[8];
        float bias = b3[j];
#pragma unroll
        for (int e = 0; e < 8; ++e) acc[e] = bias;
        for (int k4 = 0; k4 < 32; ++k4) {
            float w0 = W3[(k4 * 4 + 0) * 128 + j];
            float w1 = W3[(k4 * 4 + 1) * 128 + j];
            float w2 = W3[(k4 * 4 + 2) * 128 + j];
            float w3 = W3[(k4 * 4 + 3) * 128 + j];
#pragma unroll
            for (int e = 0; e < 8; ++e) {
                const float4 v = *(const float4*)&s2[hv * 8 + e][k4 * 4];
                acc[e] += v.x * w0 + v.y * w1 + v.z * w2 + v.w * w3;
            }
        }
#pragma unroll
        for (int e = 0; e < 8; ++e)
            hb[(size_t)(n0 + hv * 8 + e) * HDIM + j] = f2bu(acc[e]);
    }
}

// ---------------------------------------------------------------- MFMA edge kernel
// R24 = R14 champion with PAIR staging: weight slices staged 16KB at a time
// (2 slices/stage, dbuf, 8 loop barriers instead of 16). Mechanism (R13
// ledger: overlap >> occupancy): per vmcnt drain, cover doubles (2 slices of
// MFMA+epilogue between issue and drain), drains halve. Cost: LDS 49152 ->
// 65536 = 2 blocks/CU (occupancy 27 -> ~18%), the cheap side of the trade
// per R13's 3->4-blocks-worth-~0 result. Epilogues 1/2 land at pair ends
// (s=7 = pair3-end, s=11 = pair5-end), still covering in-flight stage.
// Other champion pieces unchanged: swizzled Cb (no pad), meta in registers,
// A-fragment 2-stage pipeline, reg-based scatters.
// MFMA layouts (HW-verified 16x16x32 bf16): A[m=l16][k=quad*8+j],
// B[k=quad*8+j][n=l16], D[m=quad*4+r][n=l16].
__global__ __launch_bounds__(256, 2) void edge_mfma_kernel(
    const unsigned short* __restrict__ hb, const float* __restrict__ pos,
    const int* __restrict__ rowS, const int* __restrict__ colS,
    const unsigned short* __restrict__ wt,     // [16 slice][4096] unified
    const float* __restrict__ w1d,
    const float* __restrict__ eb1, const float* __restrict__ eb2,
    const float* __restrict__ cb1, const float* __restrict__ cw2,
    float* __restrict__ agg, float* __restrict__ cu)
{
    __shared__ __align__(16) unsigned short Cb[128 * 128];   // h1/m, XOR-swizzled
    __shared__ __align__(16) unsigned short Bbuf[2][8192];   // dbuf slice-PAIRS

    const int tid = threadIdx.x;
    const int e0 = blockIdx.x * 128;
    const int L = tid & 63;
    const int w = tid >> 6;
    const int quad = L >> 4, l16 = L & 15;
    const int m0 = w * 32;

    stage_pair(wt, Bbuf[0], w);   // pair 0 (slices 0,1) in flight during setup

    // per-lane meta: lane owns edge m0 + (L&31) (both 32-lane halves identical)
    const int eloc = L & 31;
    int rowreg, colreg;
    float dsqreg, dxr, dyr, dzr;
    {
        const int eg = e0 + m0 + eloc;
        rowreg = rowS[eg];
        colreg = colS[eg];
        dxr = pos[rowreg * 3 + 0] - pos[colreg * 3 + 0];
        dyr = pos[rowreg * 3 + 1] - pos[colreg * 3 + 1];
        dzr = pos[rowreg * 3 + 2] - pos[colreg * 3 + 2];
        dsqreg = dxr * dxr + dyr * dyr + dzr * dzr;
    }
    // GEMM1 operand rows (same-wave register shuffles, no barrier needed)
    const int r0 = __shfl(rowreg, l16);
    const int r1 = __shfl(rowreg, 16 + l16);
    const int c0 = __shfl(colreg, l16);
    const int c1 = __shfl(colreg, 16 + l16);

    // slice-0 A fragments (regs only, pre-barrier)
    bf16x8 aCur0, aCur1, aNxt0, aNxt1;
    {
        const int kk = quad * 8;
        aCur0 = *(const bf16x8*)(hb + (size_t)r0 * HDIM + kk);
        aCur1 = *(const bf16x8*)(hb + (size_t)r1 * HDIM + kk);
    }
    __syncthreads();   // pair 0 staged

    f32x4 acc[2][8];
    const f32x4 zero = {0.f, 0.f, 0.f, 0.f};
#pragma unroll
    for (int mt = 0; mt < 2; ++mt)
#pragma unroll
        for (int nt = 0; nt < 8; ++nt) acc[mt][nt] = zero;

    // ---------- 8-pair pipeline (dbuf, 1 barrier/pair; slices s = 2t+u):
    //   s 0-7  : GEMM1 ef[128x256(+dsq)] @ eW1   (A from reg pipeline)
    //   s 8-11 : GEMM2 h1 @ eW2 -> m             (A from own Cb rows)
    //   s 12-15: GEMM3 m @ cW1                   (A from own Cb rows)
#pragma unroll
    for (int t = 0; t < 8; ++t) {
        if (t) __syncthreads();          // Bbuf[t&1] staged; prev buf reads done
        if (t < 7) stage_pair(wt + (size_t)(t + 1) * 8192, Bbuf[(t + 1) & 1], w);

#pragma unroll
        for (int u = 0; u < 2; ++u) {
            const int s = 2 * t + u;

            // prefetch next slice's A-fragments (GEMM1 only)
            if (s < 7) {
                const int kk = ((s + 1) & 3) * 32 + quad * 8;
                const int nn0 = (s + 1 < 4) ? r0 : c0;
                const int nn1 = (s + 1 < 4) ? r1 : c1;
                aNxt0 = *(const bf16x8*)(hb + (size_t)nn0 * HDIM + kk);
                aNxt1 = *(const bf16x8*)(hb + (size_t)nn1 * HDIM + kk);
            }

            const unsigned short* bp = Bbuf[t & 1] + u * 4096 + quad * 1024;
            bf16x8 a0, a1;
            if (s < 8) {
                a0 = aCur0; a1 = aCur1;
            } else {
                const int kk2 = ((s - 8) & 3) * 64 + quad * 16;   // byte col
                a0 = *(const bf16x8*)((const char*)Cb + ((((m0 + l16) << 8) + kk2) ^ (((m0 + l16) & 7) << 4)));
                a1 = *(const bf16x8*)((const char*)Cb + ((((m0 + 16 + l16) << 8) + kk2) ^ (((m0 + 16 + l16) & 7) << 4)));
            }
#pragma unroll
            for (int nt = 0; nt < 8; ++nt) {
                bf16x8 b = *(const bf16x8*)&bp[(nt * 16 + l16) * 8];
                acc[0][nt] = __builtin_amdgcn_mfma_f32_16x16x32_bf16(a0, b, acc[0][nt], 0, 0, 0);
                acc[1][nt] = __builtin_amdgcn_mfma_f32_16x16x32_bf16(a1, b, acc[1][nt], 0, 0, 0);
            }
            if (s < 7) { aCur0 = aNxt0; aCur1 = aNxt1; }

            if (s == 7) {
                // epilogue1 (pair3 end; covers in-flight pair-4 stage)
#pragma unroll
                for (int nt = 0; nt < 8; ++nt) {
                    const int n = nt * 16 + l16;
                    const float wd = w1d[n];
                    const float bias = eb1[n];
#pragma unroll
                    for (int mt = 0; mt < 2; ++mt)
#pragma unroll
                        for (int r = 0; r < 4; ++r) {
                            const int el = mt * 16 + quad * 4 + r;
                            const int m = m0 + el;
                            const float dsq = __shfl(dsqreg, el);
                            *(unsigned short*)((char*)Cb + cb_byte(m, n)) =
                                f2bu(silu_f(acc[mt][nt][r] + bias + dsq * wd));
                        }
                }
#pragma unroll
                for (int mt = 0; mt < 2; ++mt)
#pragma unroll
                    for (int nt = 0; nt < 8; ++nt) acc[mt][nt] = zero;
            } else if (s == 11) {
                // epilogue2 (pair5 end; covers in-flight pair-6 stage)
#pragma unroll
                for (int nt = 0; nt < 8; ++nt) {
                    const int n = nt * 16 + l16;
                    const float bias = eb2[n];
#pragma unroll
                    for (int mt = 0; mt < 2; ++mt)
#pragma unroll
                        for (int r = 0; r < 4; ++r) {
                            const int m = m0 + mt * 16 + quad * 4 + r;
                            *(unsigned short*)((char*)Cb + cb_byte(m, n)) =
                                f2bu(silu_f(acc[mt][nt][r] + bias));
                        }
                }
#pragma unroll
                for (int mt = 0; mt < 2; ++mt)
#pragma unroll
                    for (int nt = 0; nt < 8; ++nt) acc[mt][nt] = zero;
            }
        }
    }
    // After loop: last barrier at t=7 top -> all waves done with Bbuf[0]
    // (pair 6); pair 7 lives in Bbuf[1]. Bbuf[0] free for cw bounce.

    // ---------- epilogue3: cw = silu(c1+cb1) . cW2, 16-lane reduce -> Bbuf[0]
    float* cwbuf = (float*)Bbuf[0];
    {
        float sv[2][4] = {{0.f, 0.f, 0.f, 0.f}, {0.f, 0.f, 0.f, 0.f}};
#pragma unroll
        for (int nt = 0; nt < 8; ++nt) {
            const int n = nt * 16 + l16;
            const float bias = cb1[n];
            const float wv = cw2[n];
#pragma unroll
            for (int mt = 0; mt < 2; ++mt)
#pragma unroll
                for (int r = 0; r < 4; ++r)
                    sv[mt][r] += silu_f(acc[mt][nt][r] + bias) * wv;
        }
#pragma unroll
        for (int mt = 0; mt < 2; ++mt)
#pragma unroll
            for (int r = 0; r < 4; ++r) {
                float v = sv[mt][r];
                v += __shfl_xor(v, 1);
                v += __shfl_xor(v, 2);
                v += __shfl_xor(v, 4);
                v += __shfl_xor(v, 8);
                if (l16 == 0)
                    cwbuf[m0 + mt * 16 + quad * 4 + r] = v;   // own-wave region
            }
    }
    // NO barrier: scatters below touch only this wave's own rows/regs.

    // ---------- coord scatter: per-wave 32-lane segmented scan (rows sorted)
    if (L < 32) {
        const int row = rowreg;                  // lane L owns edge m0+L
        const float cwv = cwbuf[m0 + L];         // same-wave DS order
        float vx = cwv * dxr;
        float vy = cwv * dyr;
        float vz = cwv * dzr;
#pragma unroll
        for (int d = 1; d < 32; d <<= 1) {
            float ux = __shfl_up(vx, d);
            float uy = __shfl_up(vy, d);
            float uz = __shfl_up(vz, d);
            int rup = __shfl_up(row, d);
            if (L >= d && rup == row) { vx += ux; vy += uy; vz += uz; }
        }
        int rdn = __shfl_down(row, 1);
        if (L == 31 || rdn != row) {          // segment tail: holds segment sum
            atomicAdd(&cu[row * 3 + 0], vx);
            atomicAdd(&cu[row * 3 + 1], vy);
            atomicAdd(&cu[row * 3 + 2], vz);
        }
    }

    // ---------- agg scatter: own 32 edges, ballot boundary-mask + full unroll
    // lane p handles channels 2p, 2p+1; branches are wave-uniform (mask bits).
    {
        const int p = L;
        const int eb = m0;
        const int i31 = L & 31;
        const int myrow = rowreg;                // lane i31's edge row
        const int prow = __shfl_up(myrow, 1);
        unsigned long long bm64 = __ballot(i31 != 0 && myrow != prow);
        unsigned int bm = (unsigned int)bm64;    // bits from lanes 0..31
        int curr = __shfl(rowreg, 0);
        float s0 = 0.0f, s1 = 0.0f;
#pragma unroll
        for (int i = 0; i < 32; ++i) {
            const int e = eb + i;
            unsigned int v = *(const unsigned int*)((const char*)Cb + (((e << 8) + 4 * p) ^ ((e & 7) << 4)));
            if (i && (bm & (1u << i))) {
                atomicAdd(&agg[(size_t)curr * HDIM + 2 * p], s0);
                atomicAdd(&agg[(size_t)curr * HDIM + 2 * p + 1], s1);
                s0 = 0.0f; s1 = 0.0f;
                curr = __shfl(rowreg, i);
            }
            s0 += bu2f((unsigned short)(v & 0xffffu));
            s1 += bu2f((unsigned short)(v >> 16));
        }
        atomicAdd(&agg[(size_t)curr * HDIM + 2 * p], s0);
        atomicAdd(&agg[(size_t)curr * HDIM + 2 * p + 1], s1);
    }
}

// ---------------------------------------------------------------- MFMA node kernel
// R7/R12 structure (champion): 16 nodes x 128 ch per block, 2 waves N-SPLIT
// (wave w owns channels [w*64, w*64+64)), grid 512. 2 barriers. agg-zero
// after barrier (1) (race-safe).
__global__ __launch_bounds__(128) void node_mfma_kernel(
    const unsigned short* __restrict__ hb,
    float* __restrict__ agg,
    float* __restrict__ cu, const float* __restrict__ deg,
    const unsigned short* __restrict__ n1tb,   // [8 slice][4096]
    const unsigned short* __restrict__ n2tb,   // [4 slice][4096]
    const float* __restrict__ b1, const float* __restrict__ b2,
    const float* __restrict__ lg, const float* __restrict__ lb,
    unsigned short* __restrict__ h2b,
    float* __restrict__ pos)
{
    __shared__ __align__(16) unsigned short Cbuf[16][136];
    __shared__ float sLN[2][16][2];
    const int tid = threadIdx.x;
    const int n0 = blockIdx.x * 16;

    if (tid < 16) {
        int n = n0 + tid;
        float inv = __builtin_amdgcn_rcpf(deg[n] + 1e-6f);
        pos[n * 3 + 0] += cu[n * 3 + 0] * inv;
        pos[n * 3 + 1] += cu[n * 3 + 1] * inv;
        pos[n * 3 + 2] += cu[n * 3 + 2] * inv;
        cu[n * 3 + 0] = 0.0f;
        cu[n * 3 + 1] = 0.0f;
        cu[n * 3 + 2] = 0.0f;
    }

    const int L = tid & 63, w = tid >> 6;     // w in {0,1}: channel half
    const int quad = L >> 4, l16 = L & 15;
    const int row = n0 + l16;
    const int nb = w * 64;                    // channel base for this wave

    f32x4 acc[4];
    const f32x4 zero = {0.f, 0.f, 0.f, 0.f};

    // ---------- GEMM1: [h | agg] @ nW1, this wave's 64 output channels
#pragma unroll
    for (int nt = 0; nt < 4; ++nt) acc[nt] = zero;
#pragma unroll
    for (int kc = 0; kc < 8; ++kc) {
        bf16x8 a;
        if (kc < 4) {
            const int kk = kc * 32 + quad * 8;
            a = *(const bf16x8*)(hb + (size_t)row * HDIM + kk);
        } else {
            const int kk = (kc - 4) * 32 + quad * 8;
            const float4* p = (const float4*)(agg + (size_t)row * HDIM + kk);
            float4 u0 = p[0], u1 = p[1];
            a[0] = (short)f2bu(u0.x); a[1] = (short)f2bu(u0.y);
            a[2] = (short)f2bu(u0.z); a[3] = (short)f2bu(u0.w);
            a[4] = (short)f2bu(u1.x); a[5] = (short)f2bu(u1.y);
            a[6] = (short)f2bu(u1.z); a[7] = (short)f2bu(u1.w);
        }
        const unsigned short* bp = n1tb + (kc * 4 + quad) * 1024 + (nb + l16) * 8;
#pragma unroll
        for (int nt = 0; nt < 4; ++nt) {
            bf16x8 b = *(const bf16x8*)(bp + nt * 128);
            acc[nt] = __builtin_amdgcn_mfma_f32_16x16x32_bf16(a, b, acc[nt], 0, 0, 0);
        }
    }
#pragma unroll
    for (int nt = 0; nt < 4; ++nt) {
        const int n = nb + nt * 16 + l16;
        const float bias = b1[n];
#pragma unroll
        for (int r = 0; r < 4; ++r)
            Cbuf[quad * 4 + r][n] = f2bu(silu_f(acc[nt][r] + bias));
    }
    __syncthreads();   // (1) full rows visible; ALL waves' agg reads done

    // zero the block's agg rows (race-safe: after barrier 1)
    {
        const float4 z4 = {0.f, 0.f, 0.f, 0.f};
        float4* ap = (float4*)(agg + (size_t)(n0 + (tid >> 3)) * HDIM + (tid & 7) * 16);
#pragma unroll
        for (int i = 0; i < 4; ++i) ap[i] = z4;
    }

    // ---------- GEMM2: s1 @ nW2 -> nu (A = full-K rows, B = own n-half)
#pragma unroll
    for (int nt = 0; nt < 4; ++nt) acc[nt] = zero;
#pragma unroll
    for (int kc = 0; kc < 4; ++kc) {
        const int kk = kc * 32 + quad * 8;
        bf16x8 a = *(const bf16x8*)&Cbuf[l16][kk];
        const unsigned short* bp = n2tb + (kc * 4 + quad) * 1024 + (nb + l16) * 8;
#pragma unroll
        for (int nt = 0; nt < 4; ++nt) {
            bf16x8 b = *(const bf16x8*)(bp + nt * 128);
            acc[nt] = __builtin_amdgcn_mfma_f32_16x16x32_bf16(a, b, acc[nt], 0, 0, 0);
        }
    }

    // epilogue 2: x = h + nu + b2 ; LN partials (64 ch) ; cross-wave combine
#pragma unroll
    for (int nt = 0; nt < 4; ++nt) {
        const int n = nb + nt * 16 + l16;
        const float bias = b2[n];
#pragma unroll
        for (int r = 0; r < 4; ++r) {
            const int m = quad * 4 + r;
            acc[nt][r] += bias + bu2f(hb[(size_t)(n0 + m) * HDIM + n]);
        }
    }
#pragma unroll
    for (int r = 0; r < 4; ++r) {
        float s = 0.0f, ss = 0.0f;
#pragma unroll
        for (int nt = 0; nt < 4; ++nt) {
            float x = acc[nt][r];
            s += x; ss += x * x;
        }
#pragma unroll
        for (int d = 1; d < 16; d <<= 1) {
            s += __shfl_xor(s, d);
            ss += __shfl_xor(ss, d);
        }
        if (l16 == 0) {
            sLN[w][quad * 4 + r][0] = s;
            sLN[w][quad * 4 + r][1] = ss;
        }
    }
    __syncthreads();   // (2) both halves' partials visible
#pragma unroll
    for (int r = 0; r < 4; ++r) {
        const int m = quad * 4 + r;
        float s = sLN[0][m][0] + sLN[1][m][0];
        float ss = sLN[0][m][1] + sLN[1][m][1];
        float mu = s * (1.0f / 128.0f);
        float var = ss * (1.0f / 128.0f) - mu * mu;
        float rs = rsqrtf(fmaxf(var, 0.0f) + 1e-5f);
#pragma unroll
        for (int nt = 0; nt < 4; ++nt) {
            const int n = nb + nt * 16 + l16;
            float val = (acc[nt][r] - mu) * rs * lg[n] + lb[n];
            h2b[(size_t)(n0 + m) * HDIM + n] = f2bu(val);
        }
    }
}

// ---------------------------------------------------------------- launch
extern "C" void kernel_launch(void* const* d_in, const int* in_sizes, int n_in,
                              void* d_out, int out_size, void* d_ws, size_t ws_size,
                              hipStream_t stream) {
    const float* zF    = (const float*)d_in[0];
    const float* atomF = (const float*)d_in[1];
    const float* posI  = (const float*)d_in[2];
    const void*  ei    = d_in[3];
    const float* iW1 = (const float*)d_in[5];  const float* ib1 = (const float*)d_in[6];
    const float* iW2 = (const float*)d_in[7];  const float* ib2 = (const float*)d_in[8];
    const float* iW3 = (const float*)d_in[9];  const float* ib3 = (const float*)d_in[10];
    const float* eW1 = (const float*)d_in[11]; const float* eb1 = (const float*)d_in[12];
    const float* eW2 = (const float*)d_in[13]; const float* eb2 = (const float*)d_in[14];
    const float* nW1 = (const float*)d_in[15]; const float* nb1 = (const float*)d_in[16];
    const float* nW2 = (const float*)d_in[17]; const float* nb2 = (const float*)d_in[18];
    const float* cW1 = (const float*)d_in[19]; const float* cb1 = (const float*)d_in[20];
    const float* cW2 = (const float*)d_in[21];
    const float* lng = (const float*)d_in[22]; const float* lnb = (const float*)d_in[23];

    float* pos = (float*)d_out;   // fp32 output (verified R5)

    float* ws = (float*)d_ws;
    size_t cur = 16;
    auto carve = [&](size_t n) { float* p = ws + cur; cur += n; return p; };
    float* deg  = carve(NNODES);
    float* cu   = carve((size_t)NNODES * 3);
    float* agg  = carve((size_t)NNODES * HDIM);
    unsigned short* hbA = (unsigned short*)carve((size_t)NNODES * HDIM / 2);
    unsigned short* hbB = (unsigned short*)carve((size_t)NNODES * HDIM / 2);
    unsigned short* ewt  = (unsigned short*)carve((size_t)NLAYERS * 16 * 4096 / 2);
    unsigned short* n1tb = (unsigned short*)carve((size_t)NLAYERS * 8 * 4096 / 2);
    unsigned short* n2tb = (unsigned short*)carve((size_t)NLAYERS * 4 * 4096 / 2);
    float* w1d  = carve(NLAYERS * 128);
    int* cnt    = (int*)carve(NNODES);
    int* woff   = (int*)carve(NNODES);
    int* rowS   = (int*)carve(NEDGES);
    int* colS   = (int*)carve(NEDGES);

    hipMemsetAsync(cnt, 0, NNODES * sizeof(int), stream);
    // cnt pass also copies pos (pos_init merged); is64 probe inlined
    cnt_kernel<<<NEDGES / 256, 256, 0, stream>>>(ei, cnt, posI, pos);
    scan_kernel<<<1, 256, 0, stream>>>(cnt, woff, deg);
    scatter_kernel<<<NEDGES / 256, 256, 0, stream>>>(ei, woff, rowS, colS);

    prep_weights_kernel<<<2691, 256, 0, stream>>>(eW1, eW2, cW1, nW1, nW2,
                                                  ewt, n1tb, n2tb, w1d);
    inj_kernel<<<NNODES / 16, 256, 0, stream>>>(atomF, zF, iW1, ib1, iW2, ib2, iW3, ib3,
                                                hbA);

    // layer-0 zeroing only; node_mfma_kernel zeroes agg/cu for later layers
    hipMemsetAsync(agg, 0, (size_t)NNODES * HDIM * sizeof(float), stream);
    hipMemsetAsync(cu, 0, (size_t)NNODES * 3 * sizeof(float), stream);

    unsigned short* hb = hbA;
    unsigned short* ob = hbB;
    for (int l = 0; l < NLAYERS; ++l) {
        edge_mfma_kernel<<<NEDGES / 128, 256, 0, stream>>>(
            hb, pos, rowS, colS,
            ewt + (size_t)l * 16 * 4096,
            w1d + (size_t)l * 128,
            eb1 + l * 128, eb2 + l * 128, cb1 + l * 128, cW2 + l * 128,
            agg, cu);
        node_mfma_kernel<<<NNODES / 16, 128, 0, stream>>>(
            hb, agg, cu, deg,
            n1tb + (size_t)l * 8 * 4096,
            n2tb + (size_t)l * 4 * 4096,
            nb1 + l * 128, nb2 + l * 128,
            lng + l * 128, lnb + l * 128,
            /*h2b=*/ob, pos);
        unsigned short* tb = hb; hb = ob; ob = tb;
    }
}

// Round 16
// 624.261 us; speedup vs baseline: 1.0937x; 1.0937x over previous
//
#include <hip/hip_runtime.h>
#include <hip/hip_bf16.h>

#define NNODES 8192
#define NEDGES 262144
#define HDIM 128
#define NLAYERS 6
#define NMASK (NNODES - 1)

typedef __attribute__((ext_vector_type(8))) short bf16x8;   // 8 bf16 = 4 VGPR
typedef __attribute__((ext_vector_type(4))) float f32x4;    // MFMA acc
typedef const __attribute__((address_space(1))) void gvoid;
typedef __attribute__((address_space(3))) void svoid;

// fast silu: v_rcp instead of precise-div sequence (~1 ulp rcp, fine at bf16 out)
__device__ __forceinline__ float silu_f(float x) {
    return x * __builtin_amdgcn_rcpf(1.0f + __expf(-x));
}
// fast fp32->bf16: round-half-away via +0x8000 (2 VALU ops; inputs finite)
__device__ __forceinline__ unsigned short f2bu(float x) {
    unsigned int u; __builtin_memcpy(&u, &x, 4);
    return (unsigned short)((u + 0x8000u) >> 16);
}
__device__ __forceinline__ float bu2f(unsigned short u) {
    unsigned int v = ((unsigned int)u) << 16;
    float f; __builtin_memcpy(&f, &v, 4);
    return f;
}

// cooperative stage of one contiguous 8KB slice (4096 shorts) into LDS.
__device__ __forceinline__ void stage_slice(const unsigned short* src,
                                            unsigned short* dst, int w) {
    const unsigned short* s = src + w * 1024;
    unsigned short* d = dst + w * 1024;
    __builtin_amdgcn_global_load_lds((gvoid*)s, (svoid*)d, 16, 0, 0);
    __builtin_amdgcn_global_load_lds((gvoid*)(s + 512), (svoid*)(d + 512), 16, 0, 0);
}

// Cb XOR swizzle (T2-style): byte ^= (row&7)<<4. Keeps 16B chunks intact
// (bits 4-6 only), makes stride-256B row accesses 2-way-or-free on banks.
// (R13/R14-verified correct; conflicts 803k -> 524k.)
__device__ __forceinline__ int cb_byte(int row, int colshort) {
    return ((row << 8) + (colshort << 1)) ^ ((row & 7) << 4);
}

// is64 probe, inlined: int64 edge_index has zero high words at ei32[1,3,5,7].
__device__ __forceinline__ int probe_is64(const int* ei32) {
    return (ei32[1] == 0 && ei32[3] == 0 && ei32[5] == 0 && ei32[7] == 0) ? 1 : 0;
}
__device__ __forceinline__ int load_idx(const void* ei, int is64, int i) {
    int v = is64 ? (int)(((const long long*)ei)[i]) : ((const int*)ei)[i];
    return v & NMASK;
}

// ---------------------------------------------------------------- edge sort (counting sort by row)
// cnt pass also performs pos_init (independent work, merged to save a launch)
__global__ void cnt_kernel(const void* __restrict__ ei,
                           int* __restrict__ cnt,
                           const float* __restrict__ pin, float* __restrict__ pos) {
    int i = blockIdx.x * blockDim.x + threadIdx.x;
    if (i < NNODES * 3) pos[i] = pin[i];
    if (i < NEDGES) {
        const int is64 = probe_is64((const int*)ei);
        atomicAdd(&cnt[load_idx(ei, is64, i)], 1);
    }
}
__global__ void scan_kernel(const int* __restrict__ cnt, int* __restrict__ woff,
                            float* __restrict__ deg) {
    __shared__ int sums[256];
    const int t = threadIdx.x;
    const int base = t * 32;
    int s = 0;
#pragma unroll
    for (int i = 0; i < 32; ++i) s += cnt[base + i];
    sums[t] = s;
    __syncthreads();
    if (t == 0) {
        int run = 0;
        for (int k = 0; k < 256; ++k) { int v = sums[k]; sums[k] = run; run += v; }
    }
    __syncthreads();
    int run = sums[t];
#pragma unroll
    for (int i = 0; i < 32; ++i) {
        int c = cnt[base + i];
        woff[base + i] = run;
        deg[base + i] = (float)c;
        run += c;
    }
}
__global__ void scatter_kernel(const void* __restrict__ ei,
                               int* __restrict__ woff,
                               int* __restrict__ rowS, int* __restrict__ colS) {
    int i = blockIdx.x * blockDim.x + threadIdx.x;
    if (i < NEDGES) {
        const int is64 = probe_is64((const int*)ei);
        int r = load_idx(ei, is64, i);
        int c = load_idx(ei, is64, NEDGES + i);
        int p = atomicAdd(&woff[r], 1);
        rowS[p] = r;
        colS[p] = c;
    }
}

// ---------------------------------------------------------------- weight prep
// Unified edge-weight table: per layer 16 slices of [4 chunk][128 n][8 k]
// (slices 0-7 = eW1, 8-11 = eW2, 12-15 = cW1). k = sl*32 + ch*8 + j.
__global__ void prep_weights_kernel(const float* __restrict__ eW1,
                                    const float* __restrict__ eW2,
                                    const float* __restrict__ cW1,
                                    const float* __restrict__ nW1,
                                    const float* __restrict__ nW2,
                                    unsigned short* __restrict__ ewt,
                                    unsigned short* __restrict__ n1tb,
                                    unsigned short* __restrict__ n2tb,
                                    float* __restrict__ w1d) {
    const int TB = NLAYERS * 8 * 4 * 128 * 8;   // 196608
    const int TS = NLAYERS * 4 * 4 * 128 * 8;   // 98304
    const int TD = NLAYERS * 128;
    const int TOT = 2 * TB + 3 * TS + TD;
    for (int i = blockIdx.x * blockDim.x + threadIdx.x; i < TOT;
         i += gridDim.x * blockDim.x) {
        if (i < TB) {
            int j = i & 7, r = i >> 3;
            int n = r & 127; r >>= 7;
            int ch = r & 3; r >>= 2;
            int sl = r & 7; int l = r >> 3;
            int k = sl * 32 + ch * 8 + j;
            ewt[(size_t)(l * 16 + sl) * 4096 + ch * 1024 + n * 8 + j] =
                f2bu(eW1[((size_t)l * 257 + k) * 128 + n]);
        } else if (i < TB + TS) {
            int q = i - TB;
            int j = q & 7, r = q >> 3;
            int n = r & 127; r >>= 7;
            int ch = r & 3; r >>= 2;
            int sl = r & 3; int l = r >> 2;
            int k = sl * 32 + ch * 8 + j;
            ewt[(size_t)(l * 16 + 8 + sl) * 4096 + ch * 1024 + n * 8 + j] =
                f2bu(eW2[((size_t)l * 128 + k) * 128 + n]);
        } else if (i < TB + 2 * TS) {
            int q = i - TB - TS;
            int j = q & 7, r = q >> 3;
            int n = r & 127; r >>= 7;
            int ch = r & 3; r >>= 2;
            int sl = r & 3; int l = r >> 2;
            int k = sl * 32 + ch * 8 + j;
            ewt[(size_t)(l * 16 + 12 + sl) * 4096 + ch * 1024 + n * 8 + j] =
                f2bu(cW1[((size_t)l * 128 + k) * 128 + n]);
        } else if (i < 2 * TB + 2 * TS) {
            int q = i - TB - 2 * TS;
            int j = q & 7, r = q >> 3;
            int n = r & 127; r >>= 7;
            int ch = r & 3; r >>= 2;
            int sl = r & 7; int l = r >> 3;
            int k = sl * 32 + ch * 8 + j;
            n1tb[q] = f2bu(nW1[((size_t)l * 256 + k) * 128 + n]);
        } else if (i < 2 * TB + 3 * TS) {
            int q = i - 2 * TB - 2 * TS;
            int j = q & 7, r = q >> 3;
            int n = r & 127; r >>= 7;
            int ch = r & 3; r >>= 2;
            int sl = r & 3; int l = r >> 2;
            int k = sl * 32 + ch * 8 + j;
            n2tb[q] = f2bu(nW2[((size_t)l * 128 + k) * 128 + n]);
        } else {
            int r = i - 2 * TB - 3 * TS, l = r / 128, n = r % 128;
            w1d[r] = eW1[((size_t)l * 257 + 256) * 128 + n];
        }
    }
}

// ---------------------------------------------------------------- injection MLP (bf16 h out)
__global__ __launch_bounds__(256) void inj_kernel(
    const float* __restrict__ atom, const float* __restrict__ z,
    const float* __restrict__ W1, const float* __restrict__ b1,
    const float* __restrict__ W2, const float* __restrict__ b2,
    const float* __restrict__ W3, const float* __restrict__ b3,
    unsigned short* __restrict__ hb)
{
    __shared__ __align__(16) float in_s[16][84];
    __shared__ __align__(16) float s1[16][260];
    __shared__ __align__(16) float s2[16][132];
    const int tid = threadIdx.x;
    const int n0 = blockIdx.x * 16;

    if (tid < 80) {
        for (int e = 0; e < 16; ++e) {
            int n = n0 + e;
            in_s[e][tid] = (tid < 16) ? atom[n * 16 + tid] : z[(n >> 5) * 64 + (tid - 16)];
        }
    }
    __syncthreads();
    {
        float acc[16];
        float bias = b1[tid];
#pragma unroll
        for (int e = 0; e < 16; ++e) acc[e] = bias;
        for (int k4 = 0; k4 < 20; ++k4) {
            float w0 = W1[(k4 * 4 + 0) * 256 + tid];
            float w1 = W1[(k4 * 4 + 1) * 256 + tid];
            float w2 = W1[(k4 * 4 + 2) * 256 + tid];
            float w3 = W1[(k4 * 4 + 3) * 256 + tid];
#pragma unroll
            for (int e = 0; e < 16; ++e) {
                const float4 v = *(const float4*)&in_s[e][k4 * 4];
                acc[e] += v.x * w0 + v.y * w1 + v.z * w2 + v.w * w3;
            }
        }
#pragma unroll
        for (int e = 0; e < 16; ++e) s1[e][tid] = silu_f(acc[e]);
    }
    __syncthreads();
    const int j = tid & 127, hv = tid >> 7;
    {
        float acc[8];
        float bias = b2[j];
#pragma unroll
        for (int e = 0; e < 8; ++e) acc[e] = bias;
        for (int k4 = 0; k4 < 64; ++k4) {
            float w0 = W2[(k4 * 4 + 0) * 128 + j];
            float w1 = W2[(k4 * 4 + 1) * 128 + j];
            float w2 = W2[(k4 * 4 + 2) * 128 + j];
            float w3 = W2[(k4 * 4 + 3) * 128 + j];
#pragma unroll
            for (int e = 0; e < 8; ++e) {
                const float4 v = *(const float4*)&s1[hv * 8 + e][k4 * 4];
                acc[e] += v.x * w0 + v.y * w1 + v.z * w2 + v.w * w3;
            }
        }
#pragma unroll
        for (int e = 0; e < 8; ++e) s2[hv * 8 + e][j] = silu_f(acc[e]);
    }
    __syncthreads();
    {
        float acc[8];
        float bias = b3[j];
#pragma unroll
        for (int e = 0; e < 8; ++e) acc[e] = bias;
        for (int k4 = 0; k4 < 32; ++k4) {
            float w0 = W3[(k4 * 4 + 0) * 128 + j];
            float w1 = W3[(k4 * 4 + 1) * 128 + j];
            float w2 = W3[(k4 * 4 + 2) * 128 + j];
            float w3 = W3[(k4 * 4 + 3) * 128 + j];
#pragma unroll
            for (int e = 0; e < 8; ++e) {
                const float4 v = *(const float4*)&s2[hv * 8 + e][k4 * 4];
                acc[e] += v.x * w0 + v.y * w1 + v.z * w2 + v.w * w3;
            }
        }
#pragma unroll
        for (int e = 0; e < 8; ++e)
            hb[(size_t)(n0 + hv * 8 + e) * HDIM + j] = f2bu(acc[e]);
    }
}

// ---------------------------------------------------------------- MFMA edge kernel
// CHAMPION (R14, 624.8 us total; session ledger bracket: single-buf/4blk=92,
// THIS dbuf/3blk=75.4, pair-dbuf/2blk=84 -> interior optimum). 128 sorted
// edges x 128 ch, 4 waves. Double-buffered 8KB LDS slice staging over
// unified 16-slice table, ONE barrier per slice. GEMM1 A-operands via
// 2-stage register pair. GEMM2/3 A from own swizzled-Cb rows. Meta in
// per-lane registers (lane owns edge m0+(L&31)). Scatters: coord 32-lane
// segmented scan + tail atomics; agg ballot boundary-mask; no final
// barrier. cw bounce in dead Bbuf[0]. LDS 49152 -> 3 blocks/CU.
// MFMA layouts (HW-verified 16x16x32 bf16): A[m=l16][k=quad*8+j],
// B[k=quad*8+j][n=l16], D[m=quad*4+r][n=l16].
__global__ __launch_bounds__(256, 3) void edge_mfma_kernel(
    const unsigned short* __restrict__ hb, const float* __restrict__ pos,
    const int* __restrict__ rowS, const int* __restrict__ colS,
    const unsigned short* __restrict__ wt,     // [16 slice][4096] unified
    const float* __restrict__ w1d,
    const float* __restrict__ eb1, const float* __restrict__ eb2,
    const float* __restrict__ cb1, const float* __restrict__ cw2,
    float* __restrict__ agg, float* __restrict__ cu)
{
    __shared__ __align__(16) unsigned short Cb[128 * 128];   // h1/m, XOR-swizzled
    __shared__ __align__(16) unsigned short Bbuf[2][4096];   // double-buffered slice

    const int tid = threadIdx.x;
    const int e0 = blockIdx.x * 128;
    const int L = tid & 63;
    const int w = tid >> 6;
    const int quad = L >> 4, l16 = L & 15;
    const int m0 = w * 32;

    stage_slice(wt, Bbuf[0], w);   // slice 0 in flight during setup

    // per-lane meta: lane owns edge m0 + (L&31) (both 32-lane halves identical)
    const int eloc = L & 31;
    int rowreg, colreg;
    float dsqreg, dxr, dyr, dzr;
    {
        const int eg = e0 + m0 + eloc;
        rowreg = rowS[eg];
        colreg = colS[eg];
        dxr = pos[rowreg * 3 + 0] - pos[colreg * 3 + 0];
        dyr = pos[rowreg * 3 + 1] - pos[colreg * 3 + 1];
        dzr = pos[rowreg * 3 + 2] - pos[colreg * 3 + 2];
        dsqreg = dxr * dxr + dyr * dyr + dzr * dzr;
    }
    // GEMM1 operand rows (same-wave register shuffles, no barrier needed)
    const int r0 = __shfl(rowreg, l16);
    const int r1 = __shfl(rowreg, 16 + l16);
    const int c0 = __shfl(colreg, l16);
    const int c1 = __shfl(colreg, 16 + l16);

    // slice-0 A fragments (regs only, pre-barrier)
    bf16x8 aCur0, aCur1, aNxt0, aNxt1;
    {
        const int kk = quad * 8;
        aCur0 = *(const bf16x8*)(hb + (size_t)r0 * HDIM + kk);
        aCur1 = *(const bf16x8*)(hb + (size_t)r1 * HDIM + kk);
    }
    __syncthreads();   // slice 0 staged

    f32x4 acc[2][8];
    const f32x4 zero = {0.f, 0.f, 0.f, 0.f};
#pragma unroll
    for (int mt = 0; mt < 2; ++mt)
#pragma unroll
        for (int nt = 0; nt < 8; ++nt) acc[mt][nt] = zero;

    // ---------- unified 16-slice pipeline (dbuf, 1 barrier/slice):
    //   s 0-7  : GEMM1 ef[128x256(+dsq)] @ eW1   (A from reg pipeline)
    //   s 8-11 : GEMM2 h1 @ eW2 -> m             (A from own Cb rows)
    //   s 12-15: GEMM3 m @ cW1                   (A from own Cb rows)
#pragma unroll
    for (int s = 0; s < 16; ++s) {
        if (s) __syncthreads();          // Bbuf[s&1] staged; prev buf reads done
        if (s < 15) stage_slice(wt + (s + 1) * 4096, Bbuf[(s + 1) & 1], w);

        // prefetch next slice's A-fragments (GEMM1 only)
        if (s < 7) {
            const int kk = ((s + 1) & 3) * 32 + quad * 8;
            const int nn0 = (s + 1 < 4) ? r0 : c0;
            const int nn1 = (s + 1 < 4) ? r1 : c1;
            aNxt0 = *(const bf16x8*)(hb + (size_t)nn0 * HDIM + kk);
            aNxt1 = *(const bf16x8*)(hb + (size_t)nn1 * HDIM + kk);
        }

        const unsigned short* bp = Bbuf[s & 1] + quad * 1024;
        bf16x8 a0, a1;
        if (s < 8) {
            a0 = aCur0; a1 = aCur1;
        } else {
            const int kk2 = ((s - 8) & 3) * 64 + quad * 16;   // byte col = kk*2
            a0 = *(const bf16x8*)((const char*)Cb + ((((m0 + l16) << 8) + kk2) ^ (((m0 + l16) & 7) << 4)));
            a1 = *(const bf16x8*)((const char*)Cb + ((((m0 + 16 + l16) << 8) + kk2) ^ (((m0 + 16 + l16) & 7) << 4)));
        }
#pragma unroll
        for (int nt = 0; nt < 8; ++nt) {
            bf16x8 b = *(const bf16x8*)&bp[(nt * 16 + l16) * 8];
            acc[0][nt] = __builtin_amdgcn_mfma_f32_16x16x32_bf16(a0, b, acc[0][nt], 0, 0, 0);
            acc[1][nt] = __builtin_amdgcn_mfma_f32_16x16x32_bf16(a1, b, acc[1][nt], 0, 0, 0);
        }
        if (s < 7) { aCur0 = aNxt0; aCur1 = aNxt1; }

        if (s == 7) {
            // epilogue1 (overlaps in-flight stage(8)): h1 = silu(acc+eb1+dsq*wd)
#pragma unroll
            for (int nt = 0; nt < 8; ++nt) {
                const int n = nt * 16 + l16;
                const float wd = w1d[n];
                const float bias = eb1[n];
#pragma unroll
                for (int mt = 0; mt < 2; ++mt)
#pragma unroll
                    for (int r = 0; r < 4; ++r) {
                        const int el = mt * 16 + quad * 4 + r;   // edge in own wave
                        const int m = m0 + el;
                        const float dsq = __shfl(dsqreg, el);
                        *(unsigned short*)((char*)Cb + cb_byte(m, n)) =
                            f2bu(silu_f(acc[mt][nt][r] + bias + dsq * wd));
                    }
            }
#pragma unroll
            for (int mt = 0; mt < 2; ++mt)
#pragma unroll
                for (int nt = 0; nt < 8; ++nt) acc[mt][nt] = zero;
        } else if (s == 11) {
            // epilogue2 (overlaps stage(12)): m = silu(acc + eb2)
#pragma unroll
            for (int nt = 0; nt < 8; ++nt) {
                const int n = nt * 16 + l16;
                const float bias = eb2[n];
#pragma unroll
                for (int mt = 0; mt < 2; ++mt)
#pragma unroll
                    for (int r = 0; r < 4; ++r) {
                        const int m = m0 + mt * 16 + quad * 4 + r;
                        *(unsigned short*)((char*)Cb + cb_byte(m, n)) =
                            f2bu(silu_f(acc[mt][nt][r] + bias));
                    }
            }
#pragma unroll
            for (int mt = 0; mt < 2; ++mt)
#pragma unroll
                for (int nt = 0; nt < 8; ++nt) acc[mt][nt] = zero;
        }
    }
    // After loop: last barrier was at s=15 top -> all waves done with Bbuf[0]
    // (slice 14); slice 15 lives in Bbuf[1]. Bbuf[0] is free for cw bounce.

    // ---------- epilogue3: cw = silu(c1+cb1) . cW2, 16-lane reduce -> Bbuf[0]
    float* cwbuf = (float*)Bbuf[0];
    {
        float sv[2][4] = {{0.f, 0.f, 0.f, 0.f}, {0.f, 0.f, 0.f, 0.f}};
#pragma unroll
        for (int nt = 0; nt < 8; ++nt) {
            const int n = nt * 16 + l16;
            const float bias = cb1[n];
            const float wv = cw2[n];
#pragma unroll
            for (int mt = 0; mt < 2; ++mt)
#pragma unroll
                for (int r = 0; r < 4; ++r)
                    sv[mt][r] += silu_f(acc[mt][nt][r] + bias) * wv;
        }
#pragma unroll
        for (int mt = 0; mt < 2; ++mt)
#pragma unroll
            for (int r = 0; r < 4; ++r) {
                float v = sv[mt][r];
                v += __shfl_xor(v, 1);
                v += __shfl_xor(v, 2);
                v += __shfl_xor(v, 4);
                v += __shfl_xor(v, 8);
                if (l16 == 0)
                    cwbuf[m0 + mt * 16 + quad * 4 + r] = v;   // own-wave region
            }
    }
    // NO barrier: scatters below touch only this wave's own rows/regs.

    // ---------- coord scatter: per-wave 32-lane segmented scan (rows sorted)
    if (L < 32) {
        const int row = rowreg;                  // lane L owns edge m0+L
        const float cwv = cwbuf[m0 + L];         // same-wave DS order
        float vx = cwv * dxr;
        float vy = cwv * dyr;
        float vz = cwv * dzr;
#pragma unroll
        for (int d = 1; d < 32; d <<= 1) {
            float ux = __shfl_up(vx, d);
            float uy = __shfl_up(vy, d);
            float uz = __shfl_up(vz, d);
            int rup = __shfl_up(row, d);
            if (L >= d && rup == row) { vx += ux; vy += uy; vz += uz; }
        }
        int rdn = __shfl_down(row, 1);
        if (L == 31 || rdn != row) {          // segment tail: holds segment sum
            atomicAdd(&cu[row * 3 + 0], vx);
            atomicAdd(&cu[row * 3 + 1], vy);
            atomicAdd(&cu[row * 3 + 2], vz);
        }
    }

    // ---------- agg scatter: own 32 edges, ballot boundary-mask + full unroll
    // lane p handles channels 2p, 2p+1; branches are wave-uniform (mask bits).
    {
        const int p = L;
        const int eb = m0;
        const int i31 = L & 31;
        const int myrow = rowreg;                // lane i31's edge row
        const int prow = __shfl_up(myrow, 1);
        unsigned long long bm64 = __ballot(i31 != 0 && myrow != prow);
        unsigned int bm = (unsigned int)bm64;    // bits from lanes 0..31
        int curr = __shfl(rowreg, 0);
        float s0 = 0.0f, s1 = 0.0f;
#pragma unroll
        for (int i = 0; i < 32; ++i) {
            const int e = eb + i;
            unsigned int v = *(const unsigned int*)((const char*)Cb + (((e << 8) + 4 * p) ^ ((e & 7) << 4)));
            if (i && (bm & (1u << i))) {
                atomicAdd(&agg[(size_t)curr * HDIM + 2 * p], s0);
                atomicAdd(&agg[(size_t)curr * HDIM + 2 * p + 1], s1);
                s0 = 0.0f; s1 = 0.0f;
                curr = __shfl(rowreg, i);
            }
            s0 += bu2f((unsigned short)(v & 0xffffu));
            s1 += bu2f((unsigned short)(v >> 16));
        }
        atomicAdd(&agg[(size_t)curr * HDIM + 2 * p], s0);
        atomicAdd(&agg[(size_t)curr * HDIM + 2 * p + 1], s1);
    }
}

// ---------------------------------------------------------------- MFMA node kernel
// R7/R12 structure (champion): 16 nodes x 128 ch per block, 2 waves N-SPLIT
// (wave w owns channels [w*64, w*64+64)), grid 512. 2 barriers. agg-zero
// after barrier (1) (race-safe).
__global__ __launch_bounds__(128) void node_mfma_kernel(
    const unsigned short* __restrict__ hb,
    float* __restrict__ agg,
    float* __restrict__ cu, const float* __restrict__ deg,
    const unsigned short* __restrict__ n1tb,   // [8 slice][4096]
    const unsigned short* __restrict__ n2tb,   // [4 slice][4096]
    const float* __restrict__ b1, const float* __restrict__ b2,
    const float* __restrict__ lg, const float* __restrict__ lb,
    unsigned short* __restrict__ h2b,
    float* __restrict__ pos)
{
    __shared__ __align__(16) unsigned short Cbuf[16][136];
    __shared__ float sLN[2][16][2];
    const int tid = threadIdx.x;
    const int n0 = blockIdx.x * 16;

    if (tid < 16) {
        int n = n0 + tid;
        float inv = __builtin_amdgcn_rcpf(deg[n] + 1e-6f);
        pos[n * 3 + 0] += cu[n * 3 + 0] * inv;
        pos[n * 3 + 1] += cu[n * 3 + 1] * inv;
        pos[n * 3 + 2] += cu[n * 3 + 2] * inv;
        cu[n * 3 + 0] = 0.0f;
        cu[n * 3 + 1] = 0.0f;
        cu[n * 3 + 2] = 0.0f;
    }

    const int L = tid & 63, w = tid >> 6;     // w in {0,1}: channel half
    const int quad = L >> 4, l16 = L & 15;
    const int row = n0 + l16;
    const int nb = w * 64;                    // channel base for this wave

    f32x4 acc[4];
    const f32x4 zero = {0.f, 0.f, 0.f, 0.f};

    // ---------- GEMM1: [h | agg] @ nW1, this wave's 64 output channels
#pragma unroll
    for (int nt = 0; nt < 4; ++nt) acc[nt] = zero;
#pragma unroll
    for (int kc = 0; kc < 8; ++kc) {
        bf16x8 a;
        if (kc < 4) {
            const int kk = kc * 32 + quad * 8;
            a = *(const bf16x8*)(hb + (size_t)row * HDIM + kk);
        } else {
            const int kk = (kc - 4) * 32 + quad * 8;
            const float4* p = (const float4*)(agg + (size_t)row * HDIM + kk);
            float4 u0 = p[0], u1 = p[1];
            a[0] = (short)f2bu(u0.x); a[1] = (short)f2bu(u0.y);
            a[2] = (short)f2bu(u0.z); a[3] = (short)f2bu(u0.w);
            a[4] = (short)f2bu(u1.x); a[5] = (short)f2bu(u1.y);
            a[6] = (short)f2bu(u1.z); a[7] = (short)f2bu(u1.w);
        }
        const unsigned short* bp = n1tb + (kc * 4 + quad) * 1024 + (nb + l16) * 8;
#pragma unroll
        for (int nt = 0; nt < 4; ++nt) {
            bf16x8 b = *(const bf16x8*)(bp + nt * 128);
            acc[nt] = __builtin_amdgcn_mfma_f32_16x16x32_bf16(a, b, acc[nt], 0, 0, 0);
        }
    }
#pragma unroll
    for (int nt = 0; nt < 4; ++nt) {
        const int n = nb + nt * 16 + l16;
        const float bias = b1[n];
#pragma unroll
        for (int r = 0; r < 4; ++r)
            Cbuf[quad * 4 + r][n] = f2bu(silu_f(acc[nt][r] + bias));
    }
    __syncthreads();   // (1) full rows visible; ALL waves' agg reads done

    // zero the block's agg rows (race-safe: after barrier 1)
    {
        const float4 z4 = {0.f, 0.f, 0.f, 0.f};
        float4* ap = (float4*)(agg + (size_t)(n0 + (tid >> 3)) * HDIM + (tid & 7) * 16);
#pragma unroll
        for (int i = 0; i < 4; ++i) ap[i] = z4;
    }

    // ---------- GEMM2: s1 @ nW2 -> nu (A = full-K rows, B = own n-half)
#pragma unroll
    for (int nt = 0; nt < 4; ++nt) acc[nt] = zero;
#pragma unroll
    for (int kc = 0; kc < 4; ++kc) {
        const int kk = kc * 32 + quad * 8;
        bf16x8 a = *(const bf16x8*)&Cbuf[l16][kk];
        const unsigned short* bp = n2tb + (kc * 4 + quad) * 1024 + (nb + l16) * 8;
#pragma unroll
        for (int nt = 0; nt < 4; ++nt) {
            bf16x8 b = *(const bf16x8*)(bp + nt * 128);
            acc[nt] = __builtin_amdgcn_mfma_f32_16x16x32_bf16(a, b, acc[nt], 0, 0, 0);
        }
    }

    // epilogue 2: x = h + nu + b2 ; LN partials (64 ch) ; cross-wave combine
#pragma unroll
    for (int nt = 0; nt < 4; ++nt) {
        const int n = nb + nt * 16 + l16;
        const float bias = b2[n];
#pragma unroll
        for (int r = 0; r < 4; ++r) {
            const int m = quad * 4 + r;
            acc[nt][r] += bias + bu2f(hb[(size_t)(n0 + m) * HDIM + n]);
        }
    }
#pragma unroll
    for (int r = 0; r < 4; ++r) {
        float s = 0.0f, ss = 0.0f;
#pragma unroll
        for (int nt = 0; nt < 4; ++nt) {
            float x = acc[nt][r];
            s += x; ss += x * x;
        }
#pragma unroll
        for (int d = 1; d < 16; d <<= 1) {
            s += __shfl_xor(s, d);
            ss += __shfl_xor(ss, d);
        }
        if (l16 == 0) {
            sLN[w][quad * 4 + r][0] = s;
            sLN[w][quad * 4 + r][1] = ss;
        }
    }
    __syncthreads();   // (2) both halves' partials visible
#pragma unroll
    for (int r = 0; r < 4; ++r) {
        const int m = quad * 4 + r;
        float s = sLN[0][m][0] + sLN[1][m][0];
        float ss = sLN[0][m][1] + sLN[1][m][1];
        float mu = s * (1.0f / 128.0f);
        float var = ss * (1.0f / 128.0f) - mu * mu;
        float rs = rsqrtf(fmaxf(var, 0.0f) + 1e-5f);
#pragma unroll
        for (int nt = 0; nt < 4; ++nt) {
            const int n = nb + nt * 16 + l16;
            float val = (acc[nt][r] - mu) * rs * lg[n] + lb[n];
            h2b[(size_t)(n0 + m) * HDIM + n] = f2bu(val);
        }
    }
}

// ---------------------------------------------------------------- launch
extern "C" void kernel_launch(void* const* d_in, const int* in_sizes, int n_in,
                              void* d_out, int out_size, void* d_ws, size_t ws_size,
                              hipStream_t stream) {
    const float* zF    = (const float*)d_in[0];
    const float* atomF = (const float*)d_in[1];
    const float* posI  = (const float*)d_in[2];
    const void*  ei    = d_in[3];
    const float* iW1 = (const float*)d_in[5];  const float* ib1 = (const float*)d_in[6];
    const float* iW2 = (const float*)d_in[7];  const float* ib2 = (const float*)d_in[8];
    const float* iW3 = (const float*)d_in[9];  const float* ib3 = (const float*)d_in[10];
    const float* eW1 = (const float*)d_in[11]; const float* eb1 = (const float*)d_in[12];
    const float* eW2 = (const float*)d_in[13]; const float* eb2 = (const float*)d_in[14];
    const float* nW1 = (const float*)d_in[15]; const float* nb1 = (const float*)d_in[16];
    const float* nW2 = (const float*)d_in[17]; const float* nb2 = (const float*)d_in[18];
    const float* cW1 = (const float*)d_in[19]; const float* cb1 = (const float*)d_in[20];
    const float* cW2 = (const float*)d_in[21];
    const float* lng = (const float*)d_in[22]; const float* lnb = (const float*)d_in[23];

    float* pos = (float*)d_out;   // fp32 output (verified R5)

    float* ws = (float*)d_ws;
    size_t cur = 16;
    auto carve = [&](size_t n) { float* p = ws + cur; cur += n; return p; };
    float* deg  = carve(NNODES);
    float* cu   = carve((size_t)NNODES * 3);
    float* agg  = carve((size_t)NNODES * HDIM);
    unsigned short* hbA = (unsigned short*)carve((size_t)NNODES * HDIM / 2);
    unsigned short* hbB = (unsigned short*)carve((size_t)NNODES * HDIM / 2);
    unsigned short* ewt  = (unsigned short*)carve((size_t)NLAYERS * 16 * 4096 / 2);
    unsigned short* n1tb = (unsigned short*)carve((size_t)NLAYERS * 8 * 4096 / 2);
    unsigned short* n2tb = (unsigned short*)carve((size_t)NLAYERS * 4 * 4096 / 2);
    float* w1d  = carve(NLAYERS * 128);
    int* cnt    = (int*)carve(NNODES);
    int* woff   = (int*)carve(NNODES);
    int* rowS   = (int*)carve(NEDGES);
    int* colS   = (int*)carve(NEDGES);

    hipMemsetAsync(cnt, 0, NNODES * sizeof(int), stream);
    // cnt pass also copies pos (pos_init merged); is64 probe inlined
    cnt_kernel<<<NEDGES / 256, 256, 0, stream>>>(ei, cnt, posI, pos);
    scan_kernel<<<1, 256, 0, stream>>>(cnt, woff, deg);
    scatter_kernel<<<NEDGES / 256, 256, 0, stream>>>(ei, woff, rowS, colS);

    prep_weights_kernel<<<2691, 256, 0, stream>>>(eW1, eW2, cW1, nW1, nW2,
                                                  ewt, n1tb, n2tb, w1d);
    inj_kernel<<<NNODES / 16, 256, 0, stream>>>(atomF, zF, iW1, ib1, iW2, ib2, iW3, ib3,
                                                hbA);

    // layer-0 zeroing only; node_mfma_kernel zeroes agg/cu for later layers
    hipMemsetAsync(agg, 0, (size_t)NNODES * HDIM * sizeof(float), stream);
    hipMemsetAsync(cu, 0, (size_t)NNODES * 3 * sizeof(float), stream);

    unsigned short* hb = hbA;
    unsigned short* ob = hbB;
    for (int l = 0; l < NLAYERS; ++l) {
        edge_mfma_kernel<<<NEDGES / 128, 256, 0, stream>>>(
            hb, pos, rowS, colS,
            ewt + (size_t)l * 16 * 4096,
            w1d + (size_t)l * 128,
            eb1 + l * 128, eb2 + l * 128, cb1 + l * 128, cW2 + l * 128,
            agg, cu);
        node_mfma_kernel<<<NNODES / 16, 128, 0, stream>>>(
            hb, agg, cu, deg,
            n1tb + (size_t)l * 8 * 4096,
            n2tb + (size_t)l * 4 * 4096,
            nb1 + l * 128, nb2 + l * 128,
            lng + l * 128, lnb + l * 128,
            /*h2b=*/ob, pos);
        unsigned short* tb = hb; hb = ob; ob = tb;
    }
}